// Round 18
// baseline (701.441 us; speedup 1.0000x reference)
//
#include <hip/hip_runtime.h>
#include <math.h>

#define B_ 4
#define S_ 2048
#define D_ 512
#define H_ 8
#define L_ 4
#define DH_ 64
#define MLP_ 2048
#define BLK_ 128
#define NB_ 16
#define NEGINF -1e9f
#define NXE ((size_t)B_ * S_ * D_)   // 4,194,304 elements

typedef unsigned short u16;
typedef __attribute__((ext_vector_type(8))) short short8;
typedef __attribute__((ext_vector_type(4))) short short4v;
typedef __attribute__((ext_vector_type(4))) float f32x4;

__device__ __forceinline__ float bf2f(u16 s) {
  return __uint_as_float(((unsigned)s) << 16);
}
__device__ __forceinline__ u16 f2bf(float f) {
  unsigned u = __float_as_uint(f);
  unsigned r = (u + 0x7FFFu + ((u >> 16) & 1u)) >> 16;
  return (u16)r;
}

__device__ __forceinline__ void gll16(const void* g, void* l) {
  __builtin_amdgcn_global_load_lds(
      (const __attribute__((address_space(1))) unsigned int*)g,
      (__attribute__((address_space(3))) unsigned int*)l, 16, 0, 0);
}

// ---------------- embed + sinusoid PE (bf16 X out) ----------------
__global__ __launch_bounds__(128) void k_embed(const int* __restrict__ tokens,
                                               const float* __restrict__ embed,
                                               u16* __restrict__ x) {
  int s = blockIdx.x;             // 0..S-1
  int tid = threadIdx.x;
  const float c = -logf(10000.0f) / (float)D_;
  int d = tid * 4;
  float pe[4];
#pragma unroll
  for (int j = 0; j < 4; ++j) {
    int dd = d + j;
    int i2 = dd >> 1;
    float freq = __expf(c * (float)(2 * i2));
    float ang = (float)s * freq;
    pe[j] = (dd & 1) ? cosf(ang) : sinf(ang);
  }
#pragma unroll
  for (int b = 0; b < B_; ++b) {
    int tok = tokens[b * S_ + s];
    float4 e = *(const float4*)(embed + (size_t)tok * D_ + d);
    short4v o;
    o[0] = (short)f2bf(e.x + pe[0]);
    o[1] = (short)f2bf(e.y + pe[1]);
    o[2] = (short)f2bf(e.z + pe[2]);
    o[3] = (short)f2bf(e.w + pe[3]);
    *(short4v*)(x + (size_t)(b * S_ + s) * D_ + d) = o;
  }
}

// ---- fused residual-add + layernorm (bf16 X): X += Y; out = LN(X)*sc+bi ----
template <typename OT, bool HASY>
__global__ __launch_bounds__(256) void k_lnadd(u16* __restrict__ x,
                                               const u16* __restrict__ y,
                                               const float* __restrict__ sc,
                                               const float* __restrict__ bi,
                                               OT* __restrict__ out, int rows) {
  int row = blockIdx.x * 4 + (threadIdx.x >> 6);
  int lane = threadIdx.x & 63;
  if (row >= rows) return;
  u16* xr = x + (size_t)row * D_ + lane * 8;
  float v[8];
  short8 x8 = *(const short8*)xr;
#pragma unroll
  for (int j = 0; j < 8; ++j) v[j] = bf2f((u16)x8[j]);
  if (HASY) {
    short8 y8 = *(const short8*)(y + (size_t)row * D_ + lane * 8);
#pragma unroll
    for (int j = 0; j < 8; ++j) v[j] += bf2f((u16)y8[j]);
    short8 nx;
#pragma unroll
    for (int j = 0; j < 8; ++j) nx[j] = (short)f2bf(v[j]);
    *(short8*)xr = nx;
  }
  float sum = 0.f;
#pragma unroll
  for (int j = 0; j < 8; ++j) sum += v[j];
#pragma unroll
  for (int off = 32; off; off >>= 1) sum += __shfl_xor(sum, off);
  float mean = sum * (1.0f / D_);
  float var = 0.f;
#pragma unroll
  for (int j = 0; j < 8; ++j) { float d = v[j] - mean; var += d * d; }
#pragma unroll
  for (int off = 32; off; off >>= 1) var += __shfl_xor(var, off);
  float rstd = rsqrtf(var * (1.0f / D_) + 1e-6f);
  float o[8];
#pragma unroll
  for (int j = 0; j < 8; ++j) {
    int d = lane * 8 + j;
    o[j] = (v[j] - mean) * rstd * sc[d] + bi[d];
  }
  if constexpr (sizeof(OT) == 4) {
    float* op = (float*)out + (size_t)row * D_ + lane * 8;
    *(float4*)op = make_float4(o[0], o[1], o[2], o[3]);
    *(float4*)(op + 4) = make_float4(o[4], o[5], o[6], o[7]);
  } else {
    u16* op = (u16*)out + (size_t)row * D_ + lane * 8;
    short8 o8;
#pragma unroll
    for (int j = 0; j < 8; ++j) o8[j] = (short)f2bf(o[j]);
    *(short8*)op = o8;
  }
}

// -------- weight transpose + bf16 convert + scale: W[K][N] -> WT[N][K] --------
__global__ __launch_bounds__(256) void k_transp(const float* __restrict__ W,
                                                u16* __restrict__ WT, int K, int N,
                                                size_t wStrideZ, size_t tStrideZ,
                                                float scale) {
  __shared__ float t[32][33];
  const float* Wl = W + (size_t)blockIdx.z * wStrideZ;
  u16* WTl = WT + (size_t)blockIdx.z * tStrideZ;
  int k0 = blockIdx.x * 32, n0 = blockIdx.y * 32;
  int x = threadIdx.x & 31, y = threadIdx.x >> 5;
#pragma unroll
  for (int yy = y; yy < 32; yy += 8)
    t[yy][x] = Wl[(size_t)(k0 + yy) * N + n0 + x];
  __syncthreads();
#pragma unroll
  for (int yy = y; yy < 32; yy += 8)
    WTl[(size_t)(n0 + yy) * K + k0 + x] = f2bf(t[x][yy] * scale);
}

// fast GELU: x - x*rcp(exp(2y)+1); exact limits at +/-inf, rcp ~1ulp
__device__ __forceinline__ float gelu_f(float x) {
  float y = 0.7978845608028654f * (x + 0.044715f * x * x * x);
  float e = __expf(2.0f * y);
  return x - x * __builtin_amdgcn_rcpf(e + 1.0f);
}

enum { EPI_STORE = 0, EPI_GELU = 2, EPI_QKV = 4, EPI_BSTORE = 5 };

template <int EPI>
__device__ __forceinline__ void epilogue_elem(u16* Cb, float bv,
                                              int row, int col, int N, float alpha,
                                              float v) {
  if (EPI == EPI_STORE) {
    Cb[(size_t)row * N + col] = f2bf(v * alpha);
  } else if (EPI == EPI_QKV) {
    u16* dst = Cb + (size_t)(col >> 9) * NXE;
    dst[(size_t)row * D_ + (col & 511)] = f2bf(v);
  } else if (EPI == EPI_GELU) {
    Cb[(size_t)row * N + col] = f2bf(gelu_f(v + bv));
  } else if (EPI == EPI_BSTORE) {
    Cb[(size_t)row * N + col] = f2bf(v + bv);
  }
}

// ---- 128x128 tile, BK=32, 2-buffer, swizzled (wide-N GEMMs) ----
template <int EPI>
__global__ __launch_bounds__(256) void k_mm(const u16* __restrict__ A,
                                            const u16* __restrict__ BT,
                                            const float* __restrict__ bias,
                                            u16* __restrict__ Cb,
                                            int M, int N, int K, float alpha) {
  __shared__ u16 Al[2][128 * 32];
  __shared__ u16 Bl[2][128 * 32];
  int tid = threadIdx.x;
  int lane = tid & 63;
  int wave = tid >> 6;
  int nwg = gridDim.x * gridDim.y;
  int bid = blockIdx.y * gridDim.x + blockIdx.x;
  int cpx = nwg >> 3;
  int swz = (bid & 7) * cpx + (bid >> 3);
  int bx = swz % gridDim.x, by = swz / gridDim.x;
  int m0 = by * 128, n0 = bx * 128;
  int wm = (wave >> 1) * 64, wn = (wave & 1) * 64;
  int l15 = lane & 15, l4 = lane >> 4;

  // rule #21: linear LDS dest, inverse-swizzled global source chunk
  int schunk = (tid & 3) ^ ((tid >> 3) & 3);
  const u16* Ag0 = A + (size_t)(m0 + (tid >> 2)) * K + schunk * 8;
  const u16* Ag1 = Ag0 + (size_t)64 * K;
  const u16* Bg0 = BT + (size_t)(n0 + (tid >> 2)) * K + schunk * 8;
  const u16* Bg1 = Bg0 + (size_t)64 * K;

  auto stage = [&](int buf, int kt) {
    int k0 = kt * 32;
    char* AlB = (char*)(&Al[buf][0]) + wave * 1024;
    char* BlB = (char*)(&Bl[buf][0]) + wave * 1024;
    gll16(Ag0 + k0, AlB);
    gll16(Ag1 + k0, AlB + 4096);
    gll16(Bg0 + k0, BlB);
    gll16(Bg1 + k0, BlB + 4096);
  };

  f32x4 zero = {0.f, 0.f, 0.f, 0.f};
  f32x4 acc[4][4];
#pragma unroll
  for (int i = 0; i < 4; ++i)
#pragma unroll
    for (int j = 0; j < 4; ++j) acc[i][j] = zero;

  int NK = K >> 5;
  stage(0, 0);
  asm volatile("s_waitcnt vmcnt(0)" ::: "memory");
  __syncthreads();

  int rchunk = (l4 ^ ((l15 >> 1) & 3)) * 8;

  for (int t = 0; t < NK; ++t) {
    if (t + 1 < NK) stage((t + 1) & 1, t + 1);
    const u16* Ab = &Al[t & 1][0];
    const u16* Bb = &Bl[t & 1][0];
    short8 af[4], bf4[4];
#pragma unroll
    for (int i = 0; i < 4; ++i)
      af[i] = *(const short8*)(Ab + (wm + i * 16 + l15) * 32 + rchunk);
#pragma unroll
    for (int j = 0; j < 4; ++j)
      bf4[j] = *(const short8*)(Bb + (wn + j * 16 + l15) * 32 + rchunk);
#pragma unroll
    for (int i = 0; i < 4; ++i)
#pragma unroll
      for (int j = 0; j < 4; ++j)
        acc[i][j] = __builtin_amdgcn_mfma_f32_16x16x32_bf16(af[i], bf4[j], acc[i][j], 0, 0, 0);
    asm volatile("s_waitcnt vmcnt(0)" ::: "memory");
    __syncthreads();
  }

#pragma unroll
  for (int i = 0; i < 4; ++i)
#pragma unroll
    for (int j = 0; j < 4; ++j) {
      int col = n0 + wn + j * 16 + l15;
      float bv = (EPI == EPI_GELU || EPI == EPI_BSTORE) ? bias[col] : 0.f;
#pragma unroll
      for (int r = 0; r < 4; ++r) {
        int row = m0 + wm + i * 16 + l4 * 4 + r;
        epilogue_elem<EPI>(Cb, bv, row, col, N, alpha, acc[i][j][r]);
      }
    }
}

// ---- 64x64 tile, BK=64, 2-buffer, swizzled (narrow-N GEMMs) ----
template <int EPI>
__global__ __launch_bounds__(256) void k_mm64(const u16* __restrict__ A,
                                              const u16* __restrict__ BT,
                                              const float* __restrict__ bias,
                                              u16* __restrict__ Cb,
                                              int M, int N, int K, float alpha) {
  __shared__ u16 Al[2][64 * 64];
  __shared__ u16 Bl[2][64 * 64];
  int tid = threadIdx.x;
  int lane = tid & 63;
  int wave = tid >> 6;
  int nwg = gridDim.x * gridDim.y;
  int bid = blockIdx.y * gridDim.x + blockIdx.x;
  int cpx = nwg >> 3;
  int swz = (bid & 7) * cpx + (bid >> 3);
  int bx = swz % gridDim.x, by = swz / gridDim.x;
  int m0 = by * 64, n0 = bx * 64;
  int wm = (wave >> 1) * 32, wn = (wave & 1) * 32;
  int l15 = lane & 15, l4 = lane >> 4;

  int row0 = tid >> 3;                         // 0..31
  int lchunk = (tid & 7) ^ (row0 & 7);
  const u16* Ag0 = A + (size_t)(m0 + row0) * K + lchunk * 8;
  const u16* Ag1 = Ag0 + (size_t)32 * K;
  const u16* Bg0 = BT + (size_t)(n0 + row0) * K + lchunk * 8;
  const u16* Bg1 = Bg0 + (size_t)32 * K;

  auto stage = [&](int buf, int kt) {
    int k0 = kt * 64;
    char* AlB = (char*)(&Al[buf][0]) + (wave * 64) * 16;
    char* BlB = (char*)(&Bl[buf][0]) + (wave * 64) * 16;
    gll16(Ag0 + k0, AlB);
    gll16(Ag1 + k0, AlB + 256 * 16);
    gll16(Bg0 + k0, BlB);
    gll16(Bg1 + k0, BlB + 256 * 16);
  };

  f32x4 zero = {0.f, 0.f, 0.f, 0.f};
  f32x4 acc[2][2];
#pragma unroll
  for (int i = 0; i < 2; ++i)
#pragma unroll
    for (int j = 0; j < 2; ++j) acc[i][j] = zero;

  int NK = K >> 6;
  stage(0, 0);
  asm volatile("s_waitcnt vmcnt(0)" ::: "memory");
  __syncthreads();

  for (int t = 0; t < NK; ++t) {
    if (t + 1 < NK) stage((t + 1) & 1, t + 1);
    const u16* Ab = &Al[t & 1][0];
    const u16* Bb = &Bl[t & 1][0];
    short8 af[2][2], bf4[2][2];
#pragma unroll
    for (int i = 0; i < 2; ++i) {
      int ar = wm + i * 16 + l15;
#pragma unroll
      for (int ks = 0; ks < 2; ++ks)
        af[i][ks] = *(const short8*)(Ab + ar * 64 + (((ks * 4 + l4) ^ (ar & 7))) * 8);
    }
#pragma unroll
    for (int j = 0; j < 2; ++j) {
      int br = wn + j * 16 + l15;
#pragma unroll
      for (int ks = 0; ks < 2; ++ks)
        bf4[j][ks] = *(const short8*)(Bb + br * 64 + (((ks * 4 + l4) ^ (br & 7))) * 8);
    }
#pragma unroll
    for (int ks = 0; ks < 2; ++ks)
#pragma unroll
      for (int i = 0; i < 2; ++i)
#pragma unroll
        for (int j = 0; j < 2; ++j)
          acc[i][j] = __builtin_amdgcn_mfma_f32_16x16x32_bf16(af[i][ks], bf4[j][ks], acc[i][j], 0, 0, 0);
    asm volatile("s_waitcnt vmcnt(0)" ::: "memory");
    __syncthreads();
  }

#pragma unroll
  for (int i = 0; i < 2; ++i)
#pragma unroll
    for (int j = 0; j < 2; ++j) {
      int col = n0 + wn + j * 16 + l15;
      float bv = (EPI == EPI_GELU || EPI == EPI_BSTORE) ? bias[col] : 0.f;
#pragma unroll
      for (int r = 0; r < 4; ++r) {
        int row = m0 + wm + i * 16 + l4 * 4 + r;
        epilogue_elem<EPI>(Cb, bv, row, col, N, alpha, acc[i][j][r]);
      }
    }
}

// ---- fused attention: ksum+sinkhorn+smask + sorted K/V + scores + softmax + PV ----
// flat grid 512, XCD-swizzled; LDS 65.6KB -> 2 blocks/CU; P processed in 2 k-halves
__global__ __launch_bounds__(512) void k_attn(
    const u16* __restrict__ Q, const u16* __restrict__ Kg, const u16* __restrict__ Vg,
    const float* __restrict__ sortw_l, const int* __restrict__ tokens,
    u16* __restrict__ O) {
  int bid = blockIdx.x;
  int swz = (bid & 7) * 64 + (bid >> 3);   // XCD x handles work items [64x, 64x+64)
  int n = swz & 15, h = (swz >> 4) & 7, b = swz >> 7;
  int tid = threadIdx.x;
  int lane = tid & 63;
  int w = tid >> 6;
  int l15 = lane & 15, l4 = lane >> 4;

  __shared__ u16 KV[16384];   // Kcat [256 kcat][64 dh] swizzled; later V^T [64][256]
  __shared__ __align__(16) u16 Pl[16384];   // sinkhorn ws; then P half [128 q][128 k]
  __shared__ float sbias[256];
  __shared__ float prs[NB_];

  // ---- phase 0: issue local-K gll16 (rows 0..127, source pre-swizzled) ----
#pragma unroll
  for (int s = 0; s < 2; ++s) {
    int c = s * 512 + tid;            // 16B chunk id, rows 0..127
    int r = c >> 3;
    int fs = (c & 7) ^ (r & 7);       // swizzled 16B slot in source
    gll16(Kg + (((size_t)(b * S_ + n * BLK_ + r) * H_) + h) * DH_ + fs * 8,
          (char*)KV + (s * 512 + w * 64) * 16);
  }

  // Q fragments straight from global (B-operand, held in regs)
  short8 qf0, qf1;
  {
    const u16* qp = Q + (((size_t)(b * S_ + n * BLK_ + w * 16 + l15) * H_) + h) * DH_ + l4 * 8;
    qf0 = *(const short8*)(qp);
    qf1 = *(const short8*)(qp + 32);
  }

  // local V -> registers: thread t owns (vr = t>>2, 16-wide quarter vq)
  int vr = tid >> 2, vq = (tid & 3) * 16;
  short8 vloc[2];
  {
    const u16* vbase = Vg + (((size_t)(b * S_ + n * BLK_ + vr) * H_) + h) * DH_ + vq;
    vloc[0] = *(const short8*)(vbase);
    vloc[1] = *(const short8*)(vbase + 8);
  }

  // ---- ksum into Pl float workspace (scalar form — R13-proven fastest) ----
  float* ksf = (float*)Pl;        // [16][64]
  float* sbuf = ksf + 1024;       // [256]
  float* sred = sbuf + 256;       // [16]
  {
    int nk = tid >> 5;
    int d0 = (tid & 31) * 2;
    const u16* kp = Kg + (((size_t)(b * S_ + nk * BLK_) * H_) + h) * DH_ + d0;
    float s0 = 0.f, s1 = 0.f;
    for (int c = 0; c < BLK_; ++c) {
      s0 += bf2f(kp[0]);
      s1 += bf2f(kp[1]);
      kp += H_ * DH_;
    }
    ksf[nk * 64 + d0] = s0;
    ksf[nk * 64 + d0 + 1] = s1;
  }
  __syncthreads();

  // ---- logits + sinkhorn (threads 0..255 own (sn,sm); all threads hit barriers) ----
  int sn = tid >> 4, sm = tid & 15;
  float la = 0.f;
  if (tid < 256) {
    const float* wp = sortw_l + (size_t)h * DH_ * NB_;
#pragma unroll
    for (int d = 0; d < DH_; ++d) la += ksf[sn * 64 + d] * wp[d * NB_ + sm];
  }
  for (int it = 0; it < 8; ++it) {
    if (tid < 256) sbuf[tid] = la;
    __syncthreads();
    if (tid < 256 && sm == 0) {
      float mx = sbuf[sn * 16];
      for (int t = 1; t < 16; ++t) mx = fmaxf(mx, sbuf[sn * 16 + t]);
      float s = 0.f;
      for (int t = 0; t < 16; ++t) s += __expf(sbuf[sn * 16 + t] - mx);
      sred[sn] = mx + __logf(s);
    }
    __syncthreads();
    if (tid < 256) { la -= sred[sn]; sbuf[tid] = la; }
    __syncthreads();
    if (tid < 16) {
      float mx = sbuf[tid];
      for (int t = 1; t < 16; ++t) mx = fmaxf(mx, sbuf[t * 16 + tid]);
      float s = 0.f;
      for (int t = 0; t < 16; ++t) s += __expf(sbuf[t * 16 + tid] - mx);
      sred[tid] = mx + __logf(s);
    }
    __syncthreads();
    if (tid < 256) la -= sred[sm];
    __syncthreads();
  }
  if (tid < 256) sbuf[tid] = __expf(la);
  __syncthreads();

  // ---- prs (this block's perm row) + mask bias ----
  if (tid < NB_) prs[tid] = sbuf[n * 16 + tid];
  if (tid < BLK_) {
    sbias[tid] = (tokens[b * S_ + n * BLK_ + tid] > 0) ? 0.f : NEGINF;
  } else if (tid < 256) {
    int c = tid - BLK_;
    float s = 0.f;
#pragma unroll
    for (int mm = 0; mm < NB_; ++mm)
      s += sbuf[n * 16 + mm] * ((tokens[b * S_ + mm * BLK_ + c] > 0) ? 1.f : 0.f);
    sbias[tid] = (s > 0.5f) ? 0.f : NEGINF;
  }
  __syncthreads();   // local K in LDS, prs/sbias visible

  // ---- phase 1: compute sorted-K chunks (rows 128..255) and sorted-V regs ----
#pragma unroll
  for (int s = 0; s < 2; ++s) {
    int c = 1024 + s * 512 + tid;
    int r = c >> 3;                   // 128..255
    int rs = r & 127;
    int p = c & 7;
    int ls = p ^ (r & 7);
    const u16* kp = Kg + (((size_t)(b * S_ + rs) * H_) + h) * DH_ + ls * 8;
    float ak[8] = {};
#pragma unroll
    for (int m = 0; m < NB_; ++m) {
      float pr = prs[m];
      short8 kv = *(const short8*)(kp + (size_t)m * (BLK_ * H_ * DH_));
#pragma unroll
      for (int j = 0; j < 8; ++j) ak[j] += pr * bf2f((u16)kv[j]);
    }
    short8 ok;
#pragma unroll
    for (int j = 0; j < 8; ++j) ok[j] = (short)f2bf(ak[j]);
    *(short8*)(KV + r * 64 + p * 8) = ok;
  }

  short8 vsrt[2];
  {
    const u16* vp = Vg + (((size_t)(b * S_ + vr) * H_) + h) * DH_ + vq;
    float av[16] = {};
#pragma unroll
    for (int m = 0; m < NB_; ++m) {
      float pr = prs[m];
      const u16* vm = vp + (size_t)m * (BLK_ * H_ * DH_);
      short8 v0 = *(const short8*)(vm);
      short8 v1 = *(const short8*)(vm + 8);
#pragma unroll
      for (int j = 0; j < 8; ++j) {
        av[j] += pr * bf2f((u16)v0[j]);
        av[8 + j] += pr * bf2f((u16)v1[j]);
      }
    }
#pragma unroll
    for (int j = 0; j < 8; ++j) {
      vsrt[0][j] = (short)f2bf(av[j]);
      vsrt[1][j] = (short)f2bf(av[8 + j]);
    }
  }
  __syncthreads();   // full Kcat visible

  // ---- QK^T (swapped): St[kcat][q] ----
  f32x4 zero = {0.f, 0.f, 0.f, 0.f};
  f32x4 st[16];
#pragma unroll
  for (int m = 0; m < 16; ++m) st[m] = zero;
  {
    int swk = l15 & 7;
    const u16* kb0 = KV + l15 * 64 + ((l4 ^ swk) * 8);
    const u16* kb1 = KV + l15 * 64 + (((4 + l4) ^ swk) * 8);
#pragma unroll
    for (int m = 0; m < 16; ++m) {
      short8 a0 = *(const short8*)(kb0 + m * 1024);
      short8 a1 = *(const short8*)(kb1 + m * 1024);
      st[m] = __builtin_amdgcn_mfma_f32_16x16x32_bf16(a0, qf0, st[m], 0, 0, 0);
      st[m] = __builtin_amdgcn_mfma_f32_16x16x32_bf16(a1, qf1, st[m], 0, 0, 0);
    }
  }

  // ---- softmax in-register ----
  float mx = -3.0e38f;
#pragma unroll
  for (int m = 0; m < 16; ++m)
#pragma unroll
    for (int r = 0; r < 4; ++r) {
      st[m][r] += sbias[m * 16 + l4 * 4 + r];
      mx = fmaxf(mx, st[m][r]);
    }
  mx = fmaxf(mx, __shfl_xor(mx, 16));
  mx = fmaxf(mx, __shfl_xor(mx, 32));
  float sum = 0.f;
#pragma unroll
  for (int m = 0; m < 16; ++m)
#pragma unroll
    for (int r = 0; r < 4; ++r) {
      float e = __expf(st[m][r] - mx);
      st[m][r] = e;
      sum += e;
    }
  sum += __shfl_xor(sum, 16);
  sum += __shfl_xor(sum, 32);
  float inv = 1.0f / sum;

  int q = w * 16 + l15;
  int qx = q & 31;

  // ---- P half 1 (m=0..7 -> k slots 0..31) into Pl [128 q][32 slots x4] ----
#pragma unroll
  for (int m = 0; m < 8; ++m) {
    short4v p4;
#pragma unroll
    for (int r = 0; r < 4; ++r) p4[r] = (short)f2bf(st[m][r] * inv);
    int slot = (m * 4 + l4) ^ qx;     // in [0,32)
    *(short4v*)(Pl + q * 128 + slot * 4) = p4;
  }
  __syncthreads();   // QK reads of KV done everywhere; P half1 ready

  // ---- V^T into KV; 16B-slot swizzle by (d&7) ----
#pragma unroll
  for (int half = 0; half < 2; ++half)
#pragma unroll
    for (int j = 0; j < 8; ++j) {
      int d = vq + half * 8 + j;
      KV[d * 256 + (((vr >> 3) ^ (d & 7)) * 8) + (vr & 7)] = (u16)vloc[half][j];
    }
  {
    int r2 = vr + 128;
#pragma unroll
    for (int half = 0; half < 2; ++half)
#pragma unroll
      for (int j = 0; j < 8; ++j) {
        int d = vq + half * 8 + j;
        KV[d * 256 + (((r2 >> 3) ^ (d & 7)) * 8) + (r2 & 7)] = (u16)vsrt[half][j];
      }
  }
  __syncthreads();

  // ---- PV part 1: kcat 0..127 (kk blocks 0..3) ----
  f32x4 oacc[4];
#pragma unroll
  for (int nf = 0; nf < 4; ++nf) oacc[nf] = zero;
#pragma unroll
  for (int kk = 0; kk < 4; ++kk) {
    int s0 = (kk * 8 + l4 * 2) ^ qx;
    int s1 = (kk * 8 + l4 * 2 + 1) ^ qx;
    short4v a0 = *(const short4v*)(Pl + q * 128 + s0 * 4);
    short4v a1 = *(const short4v*)(Pl + q * 128 + s1 * 4);
    short8 af;
#pragma unroll
    for (int j = 0; j < 4; ++j) { af[j] = a0[j]; af[4 + j] = a1[j]; }
#pragma unroll
    for (int nf = 0; nf < 4; ++nf) {
      int d = nf * 16 + l15;
      short8 bf = *(const short8*)(KV + d * 256 + (((kk * 4 + l4) ^ (d & 7)) * 8));
      oacc[nf] = __builtin_amdgcn_mfma_f32_16x16x32_bf16(af, bf, oacc[nf], 0, 0, 0);
    }
  }
  __syncthreads();   // PV part1 reads of Pl done

  // ---- P half 2 (m=8..15 -> local slots 0..31) ----
#pragma unroll
  for (int m = 8; m < 16; ++m) {
    short4v p4;
#pragma unroll
    for (int r = 0; r < 4; ++r) p4[r] = (short)f2bf(st[m][r] * inv);
    int slot = ((m - 8) * 4 + l4) ^ qx;   // local slot in [0,32)
    *(short4v*)(Pl + q * 128 + slot * 4) = p4;
  }
  __syncthreads();

  // ---- PV part 2: kcat 128..255 (kk blocks 4..7; local af slots same formula) ----
#pragma unroll
  for (int kk = 0; kk < 4; ++kk) {
    int s0 = (kk * 8 + l4 * 2) ^ qx;
    int s1 = (kk * 8 + l4 * 2 + 1) ^ qx;
    short4v a0 = *(const short4v*)(Pl + q * 128 + s0 * 4);
    short4v a1 = *(const short4v*)(Pl + q * 128 + s1 * 4);
    short8 af;
#pragma unroll
    for (int j = 0; j < 4; ++j) { af[j] = a0[j]; af[4 + j] = a1[j]; }
#pragma unroll
    for (int nf = 0; nf < 4; ++nf) {
      int d = nf * 16 + l15;
      short8 bf = *(const short8*)(KV + d * 256 + ((((kk + 4) * 4 + l4) ^ (d & 7)) * 8));
      oacc[nf] = __builtin_amdgcn_mfma_f32_16x16x32_bf16(af, bf, oacc[nf], 0, 0, 0);
    }
  }

  // ---- store O (bf16) ----
  u16* ob = O + (((size_t)(b * S_ + n * BLK_) * H_) + h) * DH_;
#pragma unroll
  for (int nf = 0; nf < 4; ++nf) {
    int d = nf * 16 + l15;
#pragma unroll
    for (int r = 0; r < 4; ++r) {
      int qq = w * 16 + l4 * 4 + r;
      ob[(size_t)qq * (H_ * DH_) + d] = f2bf(oacc[nf][r]);
    }
  }
}

// ---------------- launch ----------------
extern "C" void kernel_launch(void* const* d_in, const int* in_sizes, int n_in,
                              void* d_out, int out_size, void* d_ws, size_t ws_size,
                              hipStream_t stream) {
  const int* tokens = (const int*)d_in[0];
  const float* embed = (const float*)d_in[1];
  const float* ln1_s = (const float*)d_in[2];
  const float* ln1_b = (const float*)d_in[3];
  const float* wq = (const float*)d_in[4];
  const float* wk = (const float*)d_in[5];
  const float* wv = (const float*)d_in[6];
  const float* wo = (const float*)d_in[7];
  const float* sortw = (const float*)d_in[8];
  const float* ln2_s = (const float*)d_in[9];
  const float* ln2_b = (const float*)d_in[10];
  const float* w1 = (const float*)d_in[11];
  const float* b1 = (const float*)d_in[12];
  const float* w2 = (const float*)d_in[13];
  const float* b2 = (const float*)d_in[14];
  const float* lnf_s = (const float*)d_in[15];
  const float* lnf_b = (const float*)d_in[16];
  float* out = (float*)d_out;

  const size_t NX = NXE;
  u16* Xb = (u16*)d_ws;             // bf16 residual stream
  u16* HID = Xb + NX;               // B*S*MLP bf16 (4*NX)
  u16* Hbf = HID + 4 * NX;
  u16* Qb = Hbf + NX;               // Q,K,V contiguous (EPI_QKV relies on this)
  u16* Kb = Qb + NX;
  u16* Vb = Kb + NX;
  u16* Yb = Vb + NX;                // GEMM residual-branch outputs (bf16)
  u16* Ob = Hbf;                    // alias: LN1 output dead by PV time
  u16* WT = Yb + NX;
  u16* wqkvT = WT;                                // [L][1536][512]
  u16* woT = wqkvT + (size_t)L_ * 3 * D_ * D_;    // [L][512][512]
  u16* w1T = woT + (size_t)L_ * D_ * D_;          // [L][2048][512]
  u16* w2T = w1T + (size_t)L_ * D_ * MLP_;        // [L][512][2048]

  const int rows = B_ * S_;
  const size_t qkvStride = (size_t)3 * D_ * D_;

  // weight transposes (bf16, [N][K]); wq scaled by 1/sqrt(DH) at transpose time
  k_transp<<<dim3(16, 16, L_), 256, 0, stream>>>(wq, wqkvT, D_, D_, (size_t)D_ * D_, qkvStride, 0.125f);
  k_transp<<<dim3(16, 16, L_), 256, 0, stream>>>(wk, wqkvT + (size_t)512 * 512, D_, D_, (size_t)D_ * D_, qkvStride, 1.0f);
  k_transp<<<dim3(16, 16, L_), 256, 0, stream>>>(wv, wqkvT + (size_t)1024 * 512, D_, D_, (size_t)D_ * D_, qkvStride, 1.0f);
  k_transp<<<dim3(16, 16, L_), 256, 0, stream>>>(wo, woT, D_, D_, (size_t)D_ * D_, (size_t)D_ * D_, 1.0f);
  k_transp<<<dim3(16, 64, L_), 256, 0, stream>>>(w1, w1T, D_, MLP_, (size_t)D_ * MLP_, (size_t)MLP_ * D_, 1.0f);
  k_transp<<<dim3(64, 16, L_), 256, 0, stream>>>(w2, w2T, MLP_, D_, (size_t)MLP_ * D_, (size_t)D_ * MLP_, 1.0f);

  k_embed<<<S_, 128, 0, stream>>>(tokens, embed, Xb);
  // layer-0 LN1 (no residual yet)
  k_lnadd<u16, false><<<rows / 4, 256, 0, stream>>>(Xb, nullptr, ln1_s, ln1_b, Hbf, rows);

  for (int l = 0; l < L_; ++l) {
    dim3 gqkv(1536 / 128, rows / 128);   // fused QKV at 128x128: 768 blocks = 3/CU
    k_mm<EPI_QKV><<<gqkv, 256, 0, stream>>>(Hbf, wqkvT + (size_t)l * qkvStride, nullptr, Qb, rows, 1536, D_, 1.0f);
    k_attn<<<NB_ * H_ * B_, 512, 0, stream>>>(Qb, Kb, Vb, sortw + (size_t)l * H_ * DH_ * NB_, tokens, Ob);
    dim3 go(D_ / 64, rows / 64);       // wo: 1024 blocks -> Yb (bf16)
    k_mm64<EPI_STORE><<<go, 256, 0, stream>>>(Ob, woT + (size_t)l * D_ * D_, nullptr, Yb, rows, D_, D_, 1.0f);
    // X += Yb; Hbf = LN2(X)
    k_lnadd<u16, true><<<rows / 4, 256, 0, stream>>>(Xb, Yb, ln2_s + l * D_, ln2_b + l * D_, Hbf, rows);
    dim3 g2(MLP_ / 128, rows / 128);   // MLP1: 1024 blocks at 128x128
    k_mm<EPI_GELU><<<g2, 256, 0, stream>>>(Hbf, w1T + (size_t)l * D_ * MLP_, b1 + (size_t)l * MLP_, HID, rows, MLP_, D_, 1.0f);
    dim3 g3(D_ / 64, rows / 64);       // MLP2: 1024 blocks -> Yb (bf16, +b2)
    k_mm64<EPI_BSTORE><<<g3, 256, 0, stream>>>(HID, w2T + (size_t)l * MLP_ * D_, b2 + (size_t)l * D_, Yb, rows, D_, MLP_, 1.0f);
    if (l < L_ - 1) {
      // X += Yb; Hbf = LN1_{l+1}(X)
      k_lnadd<u16, true><<<rows / 4, 256, 0, stream>>>(Xb, Yb, ln1_s + (l + 1) * D_, ln1_b + (l + 1) * D_, Hbf, rows);
    }
  }
  // X += Yb; out = LNf(X)
  k_lnadd<float, true><<<rows / 4, 256, 0, stream>>>(Xb, Yb, lnf_s, lnf_b, out, rows);
}

// Round 19
// 646.724 us; speedup vs baseline: 1.0846x; 1.0846x over previous
//
#include <hip/hip_runtime.h>
#include <math.h>

#define B_ 4
#define S_ 2048
#define D_ 512
#define H_ 8
#define L_ 4
#define DH_ 64
#define MLP_ 2048
#define BLK_ 128
#define NB_ 16
#define NEGINF -1e9f
#define NXE ((size_t)B_ * S_ * D_)   // 4,194,304 elements

typedef unsigned short u16;
typedef __attribute__((ext_vector_type(8))) short short8;
typedef __attribute__((ext_vector_type(4))) short short4v;
typedef __attribute__((ext_vector_type(4))) float f32x4;

__device__ __forceinline__ float bf2f(u16 s) {
  return __uint_as_float(((unsigned)s) << 16);
}
__device__ __forceinline__ u16 f2bf(float f) {
  unsigned u = __float_as_uint(f);
  unsigned r = (u + 0x7FFFu + ((u >> 16) & 1u)) >> 16;
  return (u16)r;
}

__device__ __forceinline__ void gll16(const void* g, void* l) {
  __builtin_amdgcn_global_load_lds(
      (const __attribute__((address_space(1))) unsigned int*)g,
      (__attribute__((address_space(3))) unsigned int*)l, 16, 0, 0);
}

// ---------------- embed + sinusoid PE (bf16 X out) ----------------
__global__ __launch_bounds__(128) void k_embed(const int* __restrict__ tokens,
                                               const float* __restrict__ embed,
                                               u16* __restrict__ x) {
  int s = blockIdx.x;             // 0..S-1
  int tid = threadIdx.x;
  const float c = -logf(10000.0f) / (float)D_;
  int d = tid * 4;
  float pe[4];
#pragma unroll
  for (int j = 0; j < 4; ++j) {
    int dd = d + j;
    int i2 = dd >> 1;
    float freq = __expf(c * (float)(2 * i2));
    float ang = (float)s * freq;
    pe[j] = (dd & 1) ? cosf(ang) : sinf(ang);
  }
#pragma unroll
  for (int b = 0; b < B_; ++b) {
    int tok = tokens[b * S_ + s];
    float4 e = *(const float4*)(embed + (size_t)tok * D_ + d);
    short4v o;
    o[0] = (short)f2bf(e.x + pe[0]);
    o[1] = (short)f2bf(e.y + pe[1]);
    o[2] = (short)f2bf(e.z + pe[2]);
    o[3] = (short)f2bf(e.w + pe[3]);
    *(short4v*)(x + (size_t)(b * S_ + s) * D_ + d) = o;
  }
}

// ---- fused residual-add + layernorm (bf16 X): X += Y; out = LN(X)*sc+bi ----
template <typename OT, bool HASY>
__global__ __launch_bounds__(256) void k_lnadd(u16* __restrict__ x,
                                               const u16* __restrict__ y,
                                               const float* __restrict__ sc,
                                               const float* __restrict__ bi,
                                               OT* __restrict__ out, int rows) {
  int row = blockIdx.x * 4 + (threadIdx.x >> 6);
  int lane = threadIdx.x & 63;
  if (row >= rows) return;
  u16* xr = x + (size_t)row * D_ + lane * 8;
  float v[8];
  short8 x8 = *(const short8*)xr;
#pragma unroll
  for (int j = 0; j < 8; ++j) v[j] = bf2f((u16)x8[j]);
  if (HASY) {
    short8 y8 = *(const short8*)(y + (size_t)row * D_ + lane * 8);
#pragma unroll
    for (int j = 0; j < 8; ++j) v[j] += bf2f((u16)y8[j]);
    short8 nx;
#pragma unroll
    for (int j = 0; j < 8; ++j) nx[j] = (short)f2bf(v[j]);
    *(short8*)xr = nx;
  }
  float sum = 0.f;
#pragma unroll
  for (int j = 0; j < 8; ++j) sum += v[j];
#pragma unroll
  for (int off = 32; off; off >>= 1) sum += __shfl_xor(sum, off);
  float mean = sum * (1.0f / D_);
  float var = 0.f;
#pragma unroll
  for (int j = 0; j < 8; ++j) { float d = v[j] - mean; var += d * d; }
#pragma unroll
  for (int off = 32; off; off >>= 1) var += __shfl_xor(var, off);
  float rstd = rsqrtf(var * (1.0f / D_) + 1e-6f);
  float o[8];
#pragma unroll
  for (int j = 0; j < 8; ++j) {
    int d = lane * 8 + j;
    o[j] = (v[j] - mean) * rstd * sc[d] + bi[d];
  }
  if constexpr (sizeof(OT) == 4) {
    float* op = (float*)out + (size_t)row * D_ + lane * 8;
    *(float4*)op = make_float4(o[0], o[1], o[2], o[3]);
    *(float4*)(op + 4) = make_float4(o[4], o[5], o[6], o[7]);
  } else {
    u16* op = (u16*)out + (size_t)row * D_ + lane * 8;
    short8 o8;
#pragma unroll
    for (int j = 0; j < 8; ++j) o8[j] = (short)f2bf(o[j]);
    *(short8*)op = o8;
  }
}

// -------- weight transpose + bf16 convert + scale: W[K][N] -> WT[N][K] --------
__global__ __launch_bounds__(256) void k_transp(const float* __restrict__ W,
                                                u16* __restrict__ WT, int K, int N,
                                                size_t wStrideZ, size_t tStrideZ,
                                                float scale) {
  __shared__ float t[32][33];
  const float* Wl = W + (size_t)blockIdx.z * wStrideZ;
  u16* WTl = WT + (size_t)blockIdx.z * tStrideZ;
  int k0 = blockIdx.x * 32, n0 = blockIdx.y * 32;
  int x = threadIdx.x & 31, y = threadIdx.x >> 5;
#pragma unroll
  for (int yy = y; yy < 32; yy += 8)
    t[yy][x] = Wl[(size_t)(k0 + yy) * N + n0 + x];
  __syncthreads();
#pragma unroll
  for (int yy = y; yy < 32; yy += 8)
    WTl[(size_t)(n0 + yy) * K + k0 + x] = f2bf(t[x][yy] * scale);
}

// fast GELU: x - x*rcp(exp(2y)+1); exact limits at +/-inf, rcp ~1ulp
__device__ __forceinline__ float gelu_f(float x) {
  float y = 0.7978845608028654f * (x + 0.044715f * x * x * x);
  float e = __expf(2.0f * y);
  return x - x * __builtin_amdgcn_rcpf(e + 1.0f);
}

enum { EPI_STORE = 0, EPI_GELU = 2, EPI_QKV = 4, EPI_BSTORE = 5 };

template <int EPI>
__device__ __forceinline__ void epilogue_elem(u16* Cb, float bv,
                                              int row, int col, int N, float alpha,
                                              float v) {
  if (EPI == EPI_STORE) {
    Cb[(size_t)row * N + col] = f2bf(v * alpha);
  } else if (EPI == EPI_QKV) {
    u16* dst = Cb + (size_t)(col >> 9) * NXE;
    dst[(size_t)row * D_ + (col & 511)] = f2bf(v);
  } else if (EPI == EPI_GELU) {
    Cb[(size_t)row * N + col] = f2bf(gelu_f(v + bv));
  } else if (EPI == EPI_BSTORE) {
    Cb[(size_t)row * N + col] = f2bf(v + bv);
  }
}

// ---- 128x128 tile, BK=32, 2-buffer, swizzled (wide-N GEMMs) ----
template <int EPI>
__global__ __launch_bounds__(256) void k_mm(const u16* __restrict__ A,
                                            const u16* __restrict__ BT,
                                            const float* __restrict__ bias,
                                            u16* __restrict__ Cb,
                                            int M, int N, int K, float alpha) {
  __shared__ u16 Al[2][128 * 32];
  __shared__ u16 Bl[2][128 * 32];
  int tid = threadIdx.x;
  int lane = tid & 63;
  int wave = tid >> 6;
  int nwg = gridDim.x * gridDim.y;
  int bid = blockIdx.y * gridDim.x + blockIdx.x;
  int cpx = nwg >> 3;
  int swz = (bid & 7) * cpx + (bid >> 3);
  int bx = swz % gridDim.x, by = swz / gridDim.x;
  int m0 = by * 128, n0 = bx * 128;
  int wm = (wave >> 1) * 64, wn = (wave & 1) * 64;
  int l15 = lane & 15, l4 = lane >> 4;

  // rule #21: linear LDS dest, inverse-swizzled global source chunk
  int schunk = (tid & 3) ^ ((tid >> 3) & 3);
  const u16* Ag0 = A + (size_t)(m0 + (tid >> 2)) * K + schunk * 8;
  const u16* Ag1 = Ag0 + (size_t)64 * K;
  const u16* Bg0 = BT + (size_t)(n0 + (tid >> 2)) * K + schunk * 8;
  const u16* Bg1 = Bg0 + (size_t)64 * K;

  auto stage = [&](int buf, int kt) {
    int k0 = kt * 32;
    char* AlB = (char*)(&Al[buf][0]) + wave * 1024;
    char* BlB = (char*)(&Bl[buf][0]) + wave * 1024;
    gll16(Ag0 + k0, AlB);
    gll16(Ag1 + k0, AlB + 4096);
    gll16(Bg0 + k0, BlB);
    gll16(Bg1 + k0, BlB + 4096);
  };

  f32x4 zero = {0.f, 0.f, 0.f, 0.f};
  f32x4 acc[4][4];
#pragma unroll
  for (int i = 0; i < 4; ++i)
#pragma unroll
    for (int j = 0; j < 4; ++j) acc[i][j] = zero;

  int NK = K >> 5;
  stage(0, 0);
  asm volatile("s_waitcnt vmcnt(0)" ::: "memory");
  __syncthreads();

  int rchunk = (l4 ^ ((l15 >> 1) & 3)) * 8;

  for (int t = 0; t < NK; ++t) {
    if (t + 1 < NK) stage((t + 1) & 1, t + 1);
    const u16* Ab = &Al[t & 1][0];
    const u16* Bb = &Bl[t & 1][0];
    short8 af[4], bf4[4];
#pragma unroll
    for (int i = 0; i < 4; ++i)
      af[i] = *(const short8*)(Ab + (wm + i * 16 + l15) * 32 + rchunk);
#pragma unroll
    for (int j = 0; j < 4; ++j)
      bf4[j] = *(const short8*)(Bb + (wn + j * 16 + l15) * 32 + rchunk);
#pragma unroll
    for (int i = 0; i < 4; ++i)
#pragma unroll
      for (int j = 0; j < 4; ++j)
        acc[i][j] = __builtin_amdgcn_mfma_f32_16x16x32_bf16(af[i], bf4[j], acc[i][j], 0, 0, 0);
    asm volatile("s_waitcnt vmcnt(0)" ::: "memory");
    __syncthreads();
  }

#pragma unroll
  for (int i = 0; i < 4; ++i)
#pragma unroll
    for (int j = 0; j < 4; ++j) {
      int col = n0 + wn + j * 16 + l15;
      float bv = (EPI == EPI_GELU || EPI == EPI_BSTORE) ? bias[col] : 0.f;
#pragma unroll
      for (int r = 0; r < 4; ++r) {
        int row = m0 + wm + i * 16 + l4 * 4 + r;
        epilogue_elem<EPI>(Cb, bv, row, col, N, alpha, acc[i][j][r]);
      }
    }
}

// ---- 64x64 tile, BK=64, 2-buffer, swizzled (narrow-N GEMMs) ----
template <int EPI>
__global__ __launch_bounds__(256) void k_mm64(const u16* __restrict__ A,
                                              const u16* __restrict__ BT,
                                              const float* __restrict__ bias,
                                              u16* __restrict__ Cb,
                                              int M, int N, int K, float alpha) {
  __shared__ u16 Al[2][64 * 64];
  __shared__ u16 Bl[2][64 * 64];
  int tid = threadIdx.x;
  int lane = tid & 63;
  int wave = tid >> 6;
  int nwg = gridDim.x * gridDim.y;
  int bid = blockIdx.y * gridDim.x + blockIdx.x;
  int cpx = nwg >> 3;
  int swz = (bid & 7) * cpx + (bid >> 3);
  int bx = swz % gridDim.x, by = swz / gridDim.x;
  int m0 = by * 64, n0 = bx * 64;
  int wm = (wave >> 1) * 32, wn = (wave & 1) * 32;
  int l15 = lane & 15, l4 = lane >> 4;

  int row0 = tid >> 3;                         // 0..31
  int lchunk = (tid & 7) ^ (row0 & 7);
  const u16* Ag0 = A + (size_t)(m0 + row0) * K + lchunk * 8;
  const u16* Ag1 = Ag0 + (size_t)32 * K;
  const u16* Bg0 = BT + (size_t)(n0 + row0) * K + lchunk * 8;
  const u16* Bg1 = Bg0 + (size_t)32 * K;

  auto stage = [&](int buf, int kt) {
    int k0 = kt * 64;
    char* AlB = (char*)(&Al[buf][0]) + (wave * 64) * 16;
    char* BlB = (char*)(&Bl[buf][0]) + (wave * 64) * 16;
    gll16(Ag0 + k0, AlB);
    gll16(Ag1 + k0, AlB + 256 * 16);
    gll16(Bg0 + k0, BlB);
    gll16(Bg1 + k0, BlB + 256 * 16);
  };

  f32x4 zero = {0.f, 0.f, 0.f, 0.f};
  f32x4 acc[2][2];
#pragma unroll
  for (int i = 0; i < 2; ++i)
#pragma unroll
    for (int j = 0; j < 2; ++j) acc[i][j] = zero;

  int NK = K >> 6;
  stage(0, 0);
  asm volatile("s_waitcnt vmcnt(0)" ::: "memory");
  __syncthreads();

  for (int t = 0; t < NK; ++t) {
    if (t + 1 < NK) stage((t + 1) & 1, t + 1);
    const u16* Ab = &Al[t & 1][0];
    const u16* Bb = &Bl[t & 1][0];
    short8 af[2][2], bf4[2][2];
#pragma unroll
    for (int i = 0; i < 2; ++i) {
      int ar = wm + i * 16 + l15;
#pragma unroll
      for (int ks = 0; ks < 2; ++ks)
        af[i][ks] = *(const short8*)(Ab + ar * 64 + (((ks * 4 + l4) ^ (ar & 7))) * 8);
    }
#pragma unroll
    for (int j = 0; j < 2; ++j) {
      int br = wn + j * 16 + l15;
#pragma unroll
      for (int ks = 0; ks < 2; ++ks)
        bf4[j][ks] = *(const short8*)(Bb + br * 64 + (((ks * 4 + l4) ^ (br & 7))) * 8);
    }
#pragma unroll
    for (int ks = 0; ks < 2; ++ks)
#pragma unroll
      for (int i = 0; i < 2; ++i)
#pragma unroll
        for (int j = 0; j < 2; ++j)
          acc[i][j] = __builtin_amdgcn_mfma_f32_16x16x32_bf16(af[i][ks], bf4[j][ks], acc[i][j], 0, 0, 0);
    asm volatile("s_waitcnt vmcnt(0)" ::: "memory");
    __syncthreads();
  }

#pragma unroll
  for (int i = 0; i < 2; ++i)
#pragma unroll
    for (int j = 0; j < 2; ++j) {
      int col = n0 + wn + j * 16 + l15;
      float bv = (EPI == EPI_GELU || EPI == EPI_BSTORE) ? bias[col] : 0.f;
#pragma unroll
      for (int r = 0; r < 4; ++r) {
        int row = m0 + wm + i * 16 + l4 * 4 + r;
        epilogue_elem<EPI>(Cb, bv, row, col, N, alpha, acc[i][j][r]);
      }
    }
}

// ---- fused attention: ksum+sinkhorn+smask + sorted K/V + scores + softmax + PV ----
// flat grid 512, XCD-swizzled; scalar ksum; sinkhorn row-lse via shfl (17 barriers)
__global__ __launch_bounds__(512) void k_attn(
    const u16* __restrict__ Q, const u16* __restrict__ Kg, const u16* __restrict__ Vg,
    const float* __restrict__ sortw_l, const int* __restrict__ tokens,
    u16* __restrict__ O) {
  int bid = blockIdx.x;
  int swz = (bid & 7) * 64 + (bid >> 3);   // XCD x handles work items [64x, 64x+64)
  int n = swz & 15, h = (swz >> 4) & 7, b = swz >> 7;
  int tid = threadIdx.x;
  int lane = tid & 63;
  int w = tid >> 6;
  int l15 = lane & 15, l4 = lane >> 4;

  __shared__ u16 KV[16384];   // Kcat [256 kcat][64 dh] swizzled; later V^T [64][256]
  __shared__ __align__(16) u16 Pl[32768];   // sinkhorn ws, then P bf16 q-XOR swizzled
  __shared__ float sbias[256];
  __shared__ float prs[NB_];

  // ---- phase 0: issue local-K gll16 (rows 0..127, source pre-swizzled) ----
#pragma unroll
  for (int s = 0; s < 2; ++s) {
    int c = s * 512 + tid;            // 16B chunk id, rows 0..127
    int r = c >> 3;
    int fs = (c & 7) ^ (r & 7);       // swizzled 16B slot in source
    gll16(Kg + (((size_t)(b * S_ + n * BLK_ + r) * H_) + h) * DH_ + fs * 8,
          (char*)KV + (s * 512 + w * 64) * 16);
  }

  // Q fragments straight from global (B-operand, held in regs)
  short8 qf0, qf1;
  {
    const u16* qp = Q + (((size_t)(b * S_ + n * BLK_ + w * 16 + l15) * H_) + h) * DH_ + l4 * 8;
    qf0 = *(const short8*)(qp);
    qf1 = *(const short8*)(qp + 32);
  }

  // local V -> registers: thread t owns (vr = t>>2, 16-wide quarter vq)
  int vr = tid >> 2, vq = (tid & 3) * 16;
  short8 vloc[2];
  {
    const u16* vbase = Vg + (((size_t)(b * S_ + n * BLK_ + vr) * H_) + h) * DH_ + vq;
    vloc[0] = *(const short8*)(vbase);
    vloc[1] = *(const short8*)(vbase + 8);
  }

  // ---- ksum into Pl float workspace (scalar form — R13-proven fastest) ----
  float* ksf = (float*)Pl;        // [16][64]
  float* sbuf = ksf + 1024;       // [256]
  float* sred = sbuf + 256;       // [16]
  {
    int nk = tid >> 5;
    int d0 = (tid & 31) * 2;
    const u16* kp = Kg + (((size_t)(b * S_ + nk * BLK_) * H_) + h) * DH_ + d0;
    float s0 = 0.f, s1 = 0.f;
    for (int c = 0; c < BLK_; ++c) {
      s0 += bf2f(kp[0]);
      s1 += bf2f(kp[1]);
      kp += H_ * DH_;
    }
    ksf[nk * 64 + d0] = s0;
    ksf[nk * 64 + d0 + 1] = s1;
  }
  __syncthreads();

  // ---- logits ----
  int sn = tid >> 4, sm = tid & 15;
  float la = 0.f;
  if (tid < 256) {
    const float* wp = sortw_l + (size_t)h * DH_ * NB_;
#pragma unroll
    for (int d = 0; d < DH_; ++d) la += ksf[sn * 64 + d] * wp[d * NB_ + sm];
  }

  // ---- sinkhorn: row-lse via shfl (barrier-free), col-lse via LDS (2 bar/iter) ----
  for (int it = 0; it < 8; ++it) {
    if (tid < 256) {
      float mx = la;
      mx = fmaxf(mx, __shfl_xor(mx, 1));
      mx = fmaxf(mx, __shfl_xor(mx, 2));
      mx = fmaxf(mx, __shfl_xor(mx, 4));
      mx = fmaxf(mx, __shfl_xor(mx, 8));
      float ss = __expf(la - mx);
      ss += __shfl_xor(ss, 1);
      ss += __shfl_xor(ss, 2);
      ss += __shfl_xor(ss, 4);
      ss += __shfl_xor(ss, 8);
      la -= mx + __logf(ss);
      sbuf[tid] = la;
    }
    __syncthreads();
    if (tid < 16) {
      float mx = sbuf[tid];
      for (int t = 1; t < 16; ++t) mx = fmaxf(mx, sbuf[t * 16 + tid]);
      float s = 0.f;
      for (int t = 0; t < 16; ++t) s += __expf(sbuf[t * 16 + tid] - mx);
      sred[tid] = mx + __logf(s);
    }
    __syncthreads();
    if (tid < 256) la -= sred[sm];
  }
  if (tid < 256) sbuf[tid] = __expf(la);
  __syncthreads();

  // ---- prs (this block's perm row) + mask bias ----
  if (tid < NB_) prs[tid] = sbuf[n * 16 + tid];
  if (tid < BLK_) {
    sbias[tid] = (tokens[b * S_ + n * BLK_ + tid] > 0) ? 0.f : NEGINF;
  } else if (tid < 256) {
    int c = tid - BLK_;
    float s = 0.f;
#pragma unroll
    for (int mm = 0; mm < NB_; ++mm)
      s += sbuf[n * 16 + mm] * ((tokens[b * S_ + mm * BLK_ + c] > 0) ? 1.f : 0.f);
    sbias[tid] = (s > 0.5f) ? 0.f : NEGINF;
  }
  __syncthreads();   // local K in LDS, prs/sbias visible

  // ---- phase 1: compute sorted-K chunks (rows 128..255) and sorted-V regs ----
#pragma unroll
  for (int s = 0; s < 2; ++s) {
    int c = 1024 + s * 512 + tid;
    int r = c >> 3;                   // 128..255
    int rs = r & 127;
    int p = c & 7;
    int ls = p ^ (r & 7);
    const u16* kp = Kg + (((size_t)(b * S_ + rs) * H_) + h) * DH_ + ls * 8;
    float ak[8] = {};
#pragma unroll
    for (int m = 0; m < NB_; ++m) {
      float pr = prs[m];
      short8 kv = *(const short8*)(kp + (size_t)m * (BLK_ * H_ * DH_));
#pragma unroll
      for (int j = 0; j < 8; ++j) ak[j] += pr * bf2f((u16)kv[j]);
    }
    short8 ok;
#pragma unroll
    for (int j = 0; j < 8; ++j) ok[j] = (short)f2bf(ak[j]);
    *(short8*)(KV + r * 64 + p * 8) = ok;
  }

  short8 vsrt[2];
  {
    const u16* vp = Vg + (((size_t)(b * S_ + vr) * H_) + h) * DH_ + vq;
    float av[16] = {};
#pragma unroll
    for (int m = 0; m < NB_; ++m) {
      float pr = prs[m];
      const u16* vm = vp + (size_t)m * (BLK_ * H_ * DH_);
      short8 v0 = *(const short8*)(vm);
      short8 v1 = *(const short8*)(vm + 8);
#pragma unroll
      for (int j = 0; j < 8; ++j) {
        av[j] += pr * bf2f((u16)v0[j]);
        av[8 + j] += pr * bf2f((u16)v1[j]);
      }
    }
#pragma unroll
    for (int j = 0; j < 8; ++j) {
      vsrt[0][j] = (short)f2bf(av[j]);
      vsrt[1][j] = (short)f2bf(av[8 + j]);
    }
  }
  __syncthreads();   // full Kcat visible

  // ---- QK^T (swapped): St[kcat][q] ----
  f32x4 zero = {0.f, 0.f, 0.f, 0.f};
  f32x4 st[16];
#pragma unroll
  for (int m = 0; m < 16; ++m) st[m] = zero;
  {
    int swk = l15 & 7;
    const u16* kb0 = KV + l15 * 64 + ((l4 ^ swk) * 8);
    const u16* kb1 = KV + l15 * 64 + (((4 + l4) ^ swk) * 8);
#pragma unroll
    for (int m = 0; m < 16; ++m) {
      short8 a0 = *(const short8*)(kb0 + m * 1024);
      short8 a1 = *(const short8*)(kb1 + m * 1024);
      st[m] = __builtin_amdgcn_mfma_f32_16x16x32_bf16(a0, qf0, st[m], 0, 0, 0);
      st[m] = __builtin_amdgcn_mfma_f32_16x16x32_bf16(a1, qf1, st[m], 0, 0, 0);
    }
  }

  // ---- softmax in-register ----
  float mx = -3.0e38f;
#pragma unroll
  for (int m = 0; m < 16; ++m)
#pragma unroll
    for (int r = 0; r < 4; ++r) {
      st[m][r] += sbias[m * 16 + l4 * 4 + r];
      mx = fmaxf(mx, st[m][r]);
    }
  mx = fmaxf(mx, __shfl_xor(mx, 16));
  mx = fmaxf(mx, __shfl_xor(mx, 32));
  float sum = 0.f;
#pragma unroll
  for (int m = 0; m < 16; ++m)
#pragma unroll
    for (int r = 0; r < 4; ++r) {
      float e = __expf(st[m][r] - mx);
      st[m][r] = e;
      sum += e;
    }
  sum += __shfl_xor(sum, 16);
  sum += __shfl_xor(sum, 32);
  float inv = 1.0f / sum;

  // ---- P -> LDS (bf16, q-XOR swizzle); overwrites sinkhorn workspace (dead) ----
  int q = w * 16 + l15;
  int qx = q & 31;
#pragma unroll
  for (int m = 0; m < 16; ++m) {
    short4v p4;
#pragma unroll
    for (int r = 0; r < 4; ++r) p4[r] = (short)f2bf(st[m][r] * inv);
    int slot = (m * 4 + l4) ^ qx;
    *(short4v*)(Pl + q * 256 + slot * 4) = p4;
  }
  __syncthreads();   // QK reads of KV done everywhere; Pl ready

  // ---- V^T into KV; 16B-slot swizzle by (d&7) ----
#pragma unroll
  for (int half = 0; half < 2; ++half)
#pragma unroll
    for (int j = 0; j < 8; ++j) {
      int d = vq + half * 8 + j;
      KV[d * 256 + (((vr >> 3) ^ (d & 7)) * 8) + (vr & 7)] = (u16)vloc[half][j];
    }
  {
    int r2 = vr + 128;
#pragma unroll
    for (int half = 0; half < 2; ++half)
#pragma unroll
      for (int j = 0; j < 8; ++j) {
        int d = vq + half * 8 + j;
        KV[d * 256 + (((r2 >> 3) ^ (d & 7)) * 8) + (r2 & 7)] = (u16)vsrt[half][j];
      }
  }
  __syncthreads();

  // ---- PV: O[q][dh] = P · V ----
  f32x4 oacc[4];
#pragma unroll
  for (int nf = 0; nf < 4; ++nf) oacc[nf] = zero;
#pragma unroll
  for (int kk = 0; kk < 8; ++kk) {
    int s0 = (kk * 8 + l4 * 2) ^ qx;
    int s1 = (kk * 8 + l4 * 2 + 1) ^ qx;
    short4v a0 = *(const short4v*)(Pl + q * 256 + s0 * 4);
    short4v a1 = *(const short4v*)(Pl + q * 256 + s1 * 4);
    short8 af;
#pragma unroll
    for (int j = 0; j < 4; ++j) { af[j] = a0[j]; af[4 + j] = a1[j]; }
#pragma unroll
    for (int nf = 0; nf < 4; ++nf) {
      int d = nf * 16 + l15;
      short8 bf = *(const short8*)(KV + d * 256 + (((kk * 4 + l4) ^ (d & 7)) * 8));
      oacc[nf] = __builtin_amdgcn_mfma_f32_16x16x32_bf16(af, bf, oacc[nf], 0, 0, 0);
    }
  }

  // ---- store O (bf16) ----
  u16* ob = O + (((size_t)(b * S_ + n * BLK_) * H_) + h) * DH_;
#pragma unroll
  for (int nf = 0; nf < 4; ++nf) {
    int d = nf * 16 + l15;
#pragma unroll
    for (int r = 0; r < 4; ++r) {
      int qq = w * 16 + l4 * 4 + r;
      ob[(size_t)qq * (H_ * DH_) + d] = f2bf(oacc[nf][r]);
    }
  }
}

// ---------------- launch ----------------
extern "C" void kernel_launch(void* const* d_in, const int* in_sizes, int n_in,
                              void* d_out, int out_size, void* d_ws, size_t ws_size,
                              hipStream_t stream) {
  const int* tokens = (const int*)d_in[0];
  const float* embed = (const float*)d_in[1];
  const float* ln1_s = (const float*)d_in[2];
  const float* ln1_b = (const float*)d_in[3];
  const float* wq = (const float*)d_in[4];
  const float* wk = (const float*)d_in[5];
  const float* wv = (const float*)d_in[6];
  const float* wo = (const float*)d_in[7];
  const float* sortw = (const float*)d_in[8];
  const float* ln2_s = (const float*)d_in[9];
  const float* ln2_b = (const float*)d_in[10];
  const float* w1 = (const float*)d_in[11];
  const float* b1 = (const float*)d_in[12];
  const float* w2 = (const float*)d_in[13];
  const float* b2 = (const float*)d_in[14];
  const float* lnf_s = (const float*)d_in[15];
  const float* lnf_b = (const float*)d_in[16];
  float* out = (float*)d_out;

  const size_t NX = NXE;
  u16* Xb = (u16*)d_ws;             // bf16 residual stream
  u16* HID = Xb + NX;               // B*S*MLP bf16 (4*NX)
  u16* Hbf = HID + 4 * NX;
  u16* Qb = Hbf + NX;               // Q,K,V contiguous (EPI_QKV relies on this)
  u16* Kb = Qb + NX;
  u16* Vb = Kb + NX;
  u16* Yb = Vb + NX;                // GEMM residual-branch outputs (bf16)
  u16* Ob = Hbf;                    // alias: LN1 output dead by PV time
  u16* WT = Yb + NX;
  u16* wqkvT = WT;                                // [L][1536][512]
  u16* woT = wqkvT + (size_t)L_ * 3 * D_ * D_;    // [L][512][512]
  u16* w1T = woT + (size_t)L_ * D_ * D_;          // [L][2048][512]
  u16* w2T = w1T + (size_t)L_ * D_ * MLP_;        // [L][512][2048]

  const int rows = B_ * S_;
  const size_t qkvStride = (size_t)3 * D_ * D_;

  // weight transposes (bf16, [N][K]); wq scaled by 1/sqrt(DH) at transpose time
  k_transp<<<dim3(16, 16, L_), 256, 0, stream>>>(wq, wqkvT, D_, D_, (size_t)D_ * D_, qkvStride, 0.125f);
  k_transp<<<dim3(16, 16, L_), 256, 0, stream>>>(wk, wqkvT + (size_t)512 * 512, D_, D_, (size_t)D_ * D_, qkvStride, 1.0f);
  k_transp<<<dim3(16, 16, L_), 256, 0, stream>>>(wv, wqkvT + (size_t)1024 * 512, D_, D_, (size_t)D_ * D_, qkvStride, 1.0f);
  k_transp<<<dim3(16, 16, L_), 256, 0, stream>>>(wo, woT, D_, D_, (size_t)D_ * D_, (size_t)D_ * D_, 1.0f);
  k_transp<<<dim3(16, 64, L_), 256, 0, stream>>>(w1, w1T, D_, MLP_, (size_t)D_ * MLP_, (size_t)MLP_ * D_, 1.0f);
  k_transp<<<dim3(64, 16, L_), 256, 0, stream>>>(w2, w2T, MLP_, D_, (size_t)MLP_ * D_, (size_t)D_ * MLP_, 1.0f);

  k_embed<<<S_, 128, 0, stream>>>(tokens, embed, Xb);
  // layer-0 LN1 (no residual yet)
  k_lnadd<u16, false><<<rows / 4, 256, 0, stream>>>(Xb, nullptr, ln1_s, ln1_b, Hbf, rows);

  for (int l = 0; l < L_; ++l) {
    dim3 gqkv(1536 / 128, rows / 128);   // fused QKV at 128x128: 768 blocks = 3/CU
    k_mm<EPI_QKV><<<gqkv, 256, 0, stream>>>(Hbf, wqkvT + (size_t)l * qkvStride, nullptr, Qb, rows, 1536, D_, 1.0f);
    k_attn<<<NB_ * H_ * B_, 512, 0, stream>>>(Qb, Kb, Vb, sortw + (size_t)l * H_ * DH_ * NB_, tokens, Ob);
    dim3 go(D_ / 64, rows / 64);       // wo: 1024 blocks -> Yb (bf16)
    k_mm64<EPI_STORE><<<go, 256, 0, stream>>>(Ob, woT + (size_t)l * D_ * D_, nullptr, Yb, rows, D_, D_, 1.0f);
    // X += Yb; Hbf = LN2(X)
    k_lnadd<u16, true><<<rows / 4, 256, 0, stream>>>(Xb, Yb, ln2_s + l * D_, ln2_b + l * D_, Hbf, rows);
    dim3 g2(MLP_ / 128, rows / 128);   // MLP1: 1024 blocks at 128x128
    k_mm<EPI_GELU><<<g2, 256, 0, stream>>>(Hbf, w1T + (size_t)l * D_ * MLP_, b1 + (size_t)l * MLP_, HID, rows, MLP_, D_, 1.0f);
    dim3 g3(D_ / 64, rows / 64);       // MLP2: 1024 blocks -> Yb (bf16, +b2)
    k_mm64<EPI_BSTORE><<<g3, 256, 0, stream>>>(HID, w2T + (size_t)l * MLP_ * D_, b2 + (size_t)l * D_, Yb, rows, D_, MLP_, 1.0f);
    if (l < L_ - 1) {
      // X += Yb; Hbf = LN1_{l+1}(X)
      k_lnadd<u16, true><<<rows / 4, 256, 0, stream>>>(Xb, Yb, ln1_s + (l + 1) * D_, ln1_b + (l + 1) * D_, Hbf, rows);
    }
  }
  // X += Yb; out = LNf(X)
  k_lnadd<float, true><<<rows / 4, 256, 0, stream>>>(Xb, Yb, lnf_s, lnf_b, out, rows);
}